// Round 3
// baseline (585.393 us; speedup 1.0000x reference)
//
#include <hip/hip_runtime.h>
#include <hip/hip_bf16.h>

// Problem constants
#define T_TOK 4096
#define HID   3584
#define NH    28
#define NKV   4
#define HD    128
#define SEG   4
#define LSEQ  1024
#define KDIM  3584   // K of all GEMMs (HID == NH*HD)
#define NT_K  112    // KDIM / 32

typedef __attribute__((ext_vector_type(8))) short bf16x8;
typedef __attribute__((ext_vector_type(4))) float f32x4;

#define GLOAD16(g, l) __builtin_amdgcn_global_load_lds( \
    (const __attribute__((address_space(1))) void*)(g), \
    (__attribute__((address_space(3))) void*)(l), 16, 0, 0)

__device__ __forceinline__ unsigned short f2bf(float f) {
    unsigned u = __float_as_uint(f);
    return (unsigned short)((u + 0x7fffu + ((u >> 16) & 1u)) >> 16);
}

__device__ __forceinline__ f32x4 mfma16(bf16x8 a, bf16x8 b, f32x4 c) {
    return __builtin_amdgcn_mfma_f32_16x16x32_bf16(a, b, c, 0, 0, 0);
}

// ---------------- conversion kernels ----------------

__global__ void cvt_f32_bf16(const float* __restrict__ s, unsigned short* __restrict__ d, int n4) {
    int i = blockIdx.x * 256 + threadIdx.x;
    if (i >= n4) return;
    float4 v = reinterpret_cast<const float4*>(s)[i];
    ushort4 o;
    o.x = f2bf(v.x); o.y = f2bf(v.y); o.z = f2bf(v.z); o.w = f2bf(v.w);
    reinterpret_cast<ushort4*>(d)[i] = o;
}

__global__ void cvt_x_split(const float* __restrict__ x,
                            unsigned short* __restrict__ xu, unsigned short* __restrict__ xg) {
    int i = blockIdx.x * 256 + threadIdx.x;     // over T*HID/4
    int t = i / (HID / 4);
    int c = i - t * (HID / 4);
    float4 v = reinterpret_cast<const float4*>(x)[i];
    ushort4 o;
    o.x = f2bf(v.x); o.y = f2bf(v.y); o.z = f2bf(v.z); o.w = f2bf(v.w);
    unsigned short* dst = ((t & 1) ? xg : xu) + (size_t)(t >> 1) * HID + c * 4;
    *reinterpret_cast<ushort4*>(dst) = o;
}

// ---------------- 128x256 BK=32 ring-3 GEMM core ----------------
// A: 128 rows x KDIM (pre-offset), B: 256 rows x KDIM (weights), C = A @ B^T.
// 256 threads = 4 waves; wave w owns output cols [w*64, w*64+64): per-wave 128x64.
// LDS: 3 bufs x 24KB (A 8KB + B 16KB). Rows 64B = 4 chunks of 16B,
// phys_chunk = log_chunk ^ ((r ^ (r>>2)) & 3); written via pre-swizzled source.
__device__ __forceinline__ void gemm_bm128_core(const unsigned short* __restrict__ Aptr,
                                                const unsigned short* __restrict__ Bptr,
                                                unsigned short* ldsv, f32x4 (&acc)[8][4]) {
    const int tid = threadIdx.x;               // 0..255
    const int lane = tid & 63, w = tid >> 6;
    const int lr = lane & 15, lkg = lane >> 4;
    char* const L = (char*)ldsv;

    // staging source offsets; call j covers rows j*64 .. j*64+63 (A: j=0,1; B: j=0..3)
    size_t src_off[4];
#pragma unroll
    for (int j = 0; j < 4; j++) {
        int r = j * 64 + (tid >> 2);
        int logc = (tid & 3) ^ ((r ^ (r >> 2)) & 3);
        src_off[j] = (size_t)r * KDIM + logc * 8;
    }
    const int fsw = (lr ^ (lr >> 2)) & 3;
    const int fcol = (lkg ^ fsw) << 4;

#pragma unroll
    for (int m = 0; m < 8; m++)
#pragma unroll
        for (int n = 0; n < 4; n++) acc[m][n] = (f32x4){0.f, 0.f, 0.f, 0.f};

#define STG_P1(bufp, k0) do { \
    GLOAD16(Aptr + src_off[0] + (k0), (bufp) + tid * 16); \
    GLOAD16(Aptr + src_off[1] + (k0), (bufp) + 4096 + tid * 16); \
    GLOAD16(Bptr + src_off[0] + (k0), (bufp) + 8192 + tid * 16); } while (0)
#define STG_P2(bufp, k0) do { \
    GLOAD16(Bptr + src_off[1] + (k0), (bufp) + 12288 + tid * 16); \
    GLOAD16(Bptr + src_off[2] + (k0), (bufp) + 16384 + tid * 16); \
    GLOAD16(Bptr + src_off[3] + (k0), (bufp) + 20480 + tid * 16); } while (0)
#define RD_A(bufp, mh) do { _Pragma("unroll") for (int mm = 0; mm < 4; mm++) \
    a[mm] = *(const bf16x8*)((bufp) + ((mh) * 4 + mm) * 1024 + lr * 64 + fcol); } while (0)
#define RD_B(bufp) do { _Pragma("unroll") for (int nn = 0; nn < 4; nn++) \
    b[nn] = *(const bf16x8*)((bufp) + 8192 + (w * 64 + nn * 16 + lr) * 64 + fcol); } while (0)
#define MM(mh) do { _Pragma("unroll") for (int mm = 0; mm < 4; mm++) \
    _Pragma("unroll") for (int nn = 0; nn < 4; nn++) \
        acc[(mh) * 4 + mm][nn] = mfma16(a[mm], b[nn], acc[(mh) * 4 + mm][nn]); } while (0)
#define BAR   asm volatile("s_barrier" ::: "memory")
#define LGKM0 do { asm volatile("s_waitcnt lgkmcnt(0)" ::: "memory"); \
                   __builtin_amdgcn_sched_barrier(0); } while (0)
#define VMC6  asm volatile("s_waitcnt vmcnt(6)" ::: "memory")
#define VMC0  asm volatile("s_waitcnt vmcnt(0)" ::: "memory")
#define PHI   __builtin_amdgcn_s_setprio(1)
#define PLO   __builtin_amdgcn_s_setprio(0)

    char* b0 = L;            // buffer for K-step t
    char* b1 = L + 24576;    // t+1
    char* b2 = L + 49152;    // t+2 (staging target)
    // prologue: stage steps 0 and 1
    STG_P1(b0, 0); STG_P2(b0, 0);
    STG_P1(b1, 32); STG_P2(b1, 32);
    VMC6;   // 12 outstanding -> wait <=6 : buf0's 6 landed
    BAR;

    bf16x8 a[4], b[4];
#pragma unroll 1
    for (int t = 0; t < NT_K; ++t) {
        const int kn = (t + 2) * 32;
        const bool st = (t + 2 < NT_K);
        // P1: read A(m0-3)+B, stage half of step t+2
        RD_A(b0, 0); RD_B(b0);
        if (st) STG_P1(b2, kn);
        BAR; LGKM0; PHI; MM(0); PLO; BAR;
        // P2: read A(m4-7), stage rest of step t+2
        RD_A(b0, 1);
        if (st) STG_P2(b2, kn);
        BAR; LGKM0; PHI; MM(1); PLO;
        if (st) { VMC6; } else { VMC0; }   // drain step t+1's loads (keep t+2's in flight)
        BAR;
        char* tmp = b0; b0 = b1; b1 = b2; b2 = tmp;
    }
    VMC0;

#undef STG_P1
#undef STG_P2
#undef RD_A
#undef RD_B
#undef MM
#undef BAR
#undef LGKM0
#undef VMC6
#undef VMC0
#undef PHI
#undef PLO
}

// ---------------- fused QKV projection ----------------
// grid: (32 mblocks [0-15 par0 | 16-31 par1], 18 nblocks [14 q | 2 k | 2 v]), 256 thr
__global__ __launch_bounds__(256, 2) void qkv_gemm8(
    const unsigned short* __restrict__ xu, const unsigned short* __restrict__ xg,
    const unsigned short* __restrict__ wq0, const unsigned short* __restrict__ wk0,
    const unsigned short* __restrict__ wv0, const unsigned short* __restrict__ wq1,
    const unsigned short* __restrict__ wk1, const unsigned short* __restrict__ wv1,
    const float* __restrict__ bq0, const float* __restrict__ bk0, const float* __restrict__ bv0,
    const float* __restrict__ bq1, const float* __restrict__ bk1, const float* __restrict__ bv1,
    float* __restrict__ qo, float* __restrict__ ko, float* __restrict__ vo) {
    __shared__ unsigned short lds[36864];   // 72 KiB
    const int bm = blockIdx.x, nb = blockIdx.y;
    const int par = bm >> 4, mb = bm & 15;
    const unsigned short* A = (par ? xg : xu) + (size_t)mb * 128 * KDIM;
    const unsigned short* W;
    const float* bias;
    float* C;
    int ldc, col0;
    if (nb < 14) {
        W = (par ? wq1 : wq0) + (size_t)nb * 256 * KDIM;
        bias = (par ? bq1 : bq0); C = qo; ldc = NH * HD; col0 = nb * 256;
    } else if (nb < 16) {
        W = (par ? wk1 : wk0) + (size_t)(nb - 14) * 256 * KDIM;
        bias = (par ? bk1 : bk0); C = ko; ldc = NKV * HD; col0 = (nb - 14) * 256;
    } else {
        W = (par ? wv1 : wv0) + (size_t)(nb - 16) * 256 * KDIM;
        bias = (par ? bv1 : bv0); C = vo; ldc = NKV * HD; col0 = (nb - 16) * 256;
    }
    f32x4 acc[8][4];
    gemm_bm128_core(A, W, lds, acc);

    const int lane = threadIdx.x & 63, w = threadIdx.x >> 6;
    const int lr = lane & 15, lkg = lane >> 4;
#pragma unroll
    for (int n = 0; n < 4; n++) {
        int colt = col0 + w * 64 + n * 16 + lr;
        float bb = bias[colt];
#pragma unroll
        for (int m = 0; m < 8; m++) {
#pragma unroll
            for (int rg = 0; rg < 4; rg++) {
                int tr = mb * 128 + m * 16 + lkg * 4 + rg;
                int tok = 2 * tr + par;
                C[(size_t)tok * ldc + colt] = acc[m][n][rg] + bb;
            }
        }
    }
}

// ---------------- output projection ----------------
__global__ __launch_bounds__(256, 2) void oproj_gemm8(
    const unsigned short* __restrict__ au, const unsigned short* __restrict__ ag,
    const unsigned short* __restrict__ wo0, const unsigned short* __restrict__ wo1,
    float* __restrict__ out) {
    __shared__ unsigned short lds[36864];
    const int bm = blockIdx.x, nb = blockIdx.y;
    const int par = bm >> 4, mb = bm & 15;
    const unsigned short* A = (par ? ag : au) + (size_t)mb * 128 * KDIM;
    const unsigned short* W = (par ? wo1 : wo0) + (size_t)nb * 256 * KDIM;
    f32x4 acc[8][4];
    gemm_bm128_core(A, W, lds, acc);

    const int lane = threadIdx.x & 63, w = threadIdx.x >> 6;
    const int lr = lane & 15, lkg = lane >> 4;
#pragma unroll
    for (int n = 0; n < 4; n++) {
        int col = nb * 256 + w * 64 + n * 16 + lr;
#pragma unroll
        for (int m = 0; m < 8; m++) {
#pragma unroll
            for (int rg = 0; rg < 4; rg++) {
                int tr = mb * 128 + m * 16 + lkg * 4 + rg;
                int tok = 2 * tr + par;
                out[(size_t)tok * HID + col] = acc[m][n][rg];
            }
        }
    }
}

// ---------------- RMSNorm + RoPE (q,k) — 4 waves, no LDS ----------------
// grid (T, 8), block 256; wave w handles head by*4+w (0..27 q, 28..31 k)
__global__ void normrope2(const float* __restrict__ q, const float* __restrict__ k,
                          const float* __restrict__ cosb, const float* __restrict__ sinb,
                          const float* __restrict__ qn, const float* __restrict__ kn,
                          const float* __restrict__ qng, const float* __restrict__ kng,
                          unsigned short* __restrict__ q_bf, unsigned short* __restrict__ k_bf) {
    const int t = blockIdx.x, w = threadIdx.x >> 6, lane = threadIdx.x & 63;
    const int h = blockIdx.y * 4 + w;
    const bool isq = (h < 28);
    const float* src = isq ? q + (size_t)t * (NH * HD) + h * HD
                           : k + (size_t)t * (NKV * HD) + (h - 28) * HD;
    float v0 = src[lane], v1 = src[lane + 64];
    float ss = v0 * v0 + v1 * v1;
#pragma unroll
    for (int off = 32; off >= 1; off >>= 1) ss += __shfl_xor(ss, off, 64);
    float inv = rsqrtf(ss * (1.f / 128.f) + 1e-6f);
    const float* wn = isq ? ((t & 1) ? qng : qn) : ((t & 1) ? kng : kn);
    float n0 = v0 * inv * wn[lane], n1 = v1 * inv * wn[lane + 64];
    float c0 = cosb[(size_t)t * HD + lane], c1 = cosb[(size_t)t * HD + lane + 64];
    float s0 = sinb[(size_t)t * HD + lane], s1 = sinb[(size_t)t * HD + lane + 64];
    float o0 = n0 * c0 - n1 * s0;       // d < 64: rot = -x[d+64]
    float o1 = n1 * c1 + n0 * s1;       // d >= 64: rot = x[d-64]
    unsigned short* dst = isq ? q_bf + (size_t)t * (NH * HD) + h * HD
                              : k_bf + (size_t)t * (NKV * HD) + (h - 28) * HD;
    dst[lane] = f2bf(o0);
    dst[lane + 64] = f2bf(o1);
}

// ---------------- V transpose/convert: vT[(s*NKV+hv)*HD + d][l] ----------------
// grid (128 l-blocks of 8, 16 sh), block 128 (tid = d). Coalesced reads, 16B writes.
__global__ void vtrans(const float* __restrict__ v, unsigned short* __restrict__ vT) {
    const int lb = blockIdx.x, sh = blockIdx.y;
    const int s = sh >> 2, hv = sh & 3, d = threadIdx.x;
    unsigned short tmp[8];
#pragma unroll
    for (int i = 0; i < 8; i++) {
        float val = v[((size_t)(s * LSEQ + lb * 8 + i)) * (NKV * HD) + hv * HD + d];
        tmp[i] = f2bf(val);
    }
    *(bf16x8*)(vT + ((size_t)sh * HD + d) * LSEQ + lb * 8) = *(bf16x8*)tmp;
}

// ---------------- flash attention ----------------
__global__ __launch_bounds__(256, 2) void attn_fwd(
    const unsigned short* __restrict__ q_bf, const unsigned short* __restrict__ k_bf,
    const unsigned short* __restrict__ vT,
    unsigned short* __restrict__ au, unsigned short* __restrict__ ag) {
    __shared__ unsigned short kt[64 * 128];   // K tile  [kv(64)][d(128)]  swizzled
    __shared__ unsigned short vt[128 * 64];   // V tile  [d(128)][kv(64)]  swizzled
    __shared__ unsigned short pt[4][16 * 64]; // per-wave P [q(16)][kv(64)] swizzled

    const int qbk = 15 - blockIdx.x;          // heavy (long-K) blocks dispatch first
    const int h = blockIdx.y, s = blockIdx.z;
    const int hk = h / 7;   // GQA group of 7
    const int tid = threadIdx.x, lane = tid & 63, w = tid >> 6;
    const int lr = lane & 15, lkg = lane >> 4;

    bf16x8 qf[4];
    {
        const unsigned short* qp =
            q_bf + ((size_t)(s * LSEQ + qbk * 64 + w * 16 + lr)) * (NH * HD) + h * HD;
#pragma unroll
        for (int kk = 0; kk < 4; kk++) qf[kk] = *(const bf16x8*)(qp + kk * 32 + lkg * 8);
    }

    float m_r[4] = {-1e30f, -1e30f, -1e30f, -1e30f};
    float l_r[4] = {0.f, 0.f, 0.f, 0.f};
    f32x4 accO[8];
#pragma unroll
    for (int dn = 0; dn < 8; dn++) accO[dn] = (f32x4){0.f, 0.f, 0.f, 0.f};

    const float scale = 0.08838834764831843f;   // 1/sqrt(128)
    const int nkt = qbk + 1;

    for (int ktile = 0; ktile < nkt; ++ktile) {
        __syncthreads();
#pragma unroll
        for (int i = 0; i < 4; i++) {
            int o = i * 4096 + tid * 16;
            {   // K: rows 256B = 16 chunks
                int r = o >> 8;
                int sc = ((o >> 4) & 15) ^ (r & 7);
                GLOAD16(k_bf + ((size_t)(s * LSEQ + ktile * 64 + r)) * (NKV * HD) + hk * HD + sc * 8,
                        (char*)kt + o);
            }
            {   // V^T: rows 128B = 8 chunks
                int r = o >> 7;
                int sc = ((o >> 4) & 7) ^ (r & 7);
                GLOAD16(vT + ((size_t)((s * NKV + hk) * HD + r)) * LSEQ + ktile * 64 + sc * 8,
                        (char*)vt + o);
            }
        }
        __syncthreads();

        f32x4 accS[4];
#pragma unroll
        for (int n = 0; n < 4; n++) accS[n] = (f32x4){0.f, 0.f, 0.f, 0.f};
#pragma unroll
        for (int n = 0; n < 4; n++) {
            int r = n * 16 + lr;
#pragma unroll
            for (int kk = 0; kk < 4; kk++) {
                bf16x8 kf = *(const bf16x8*)((const char*)kt + r * 256 +
                                             (((kk * 4 + lkg) ^ (r & 7)) << 4));
                accS[n] = mfma16(qf[kk], kf, accS[n]);
            }
        }
        float mnew[4] = {-1e30f, -1e30f, -1e30f, -1e30f};
#pragma unroll
        for (int n = 0; n < 4; n++) {
            int col = ktile * 64 + n * 16 + lr;
#pragma unroll
            for (int rg = 0; rg < 4; rg++) {
                int row = qbk * 64 + w * 16 + lkg * 4 + rg;
                float sv = accS[n][rg] * scale;
                sv = (col <= row) ? sv : -1e30f;
                accS[n][rg] = sv;
                mnew[rg] = fmaxf(mnew[rg], sv);
            }
        }
#pragma unroll
        for (int off = 1; off < 16; off <<= 1)
#pragma unroll
            for (int rg = 0; rg < 4; rg++)
                mnew[rg] = fmaxf(mnew[rg], __shfl_xor(mnew[rg], off, 64));
        float alpha[4];
#pragma unroll
        for (int rg = 0; rg < 4; rg++) {
            float mc = fmaxf(m_r[rg], mnew[rg]);
            alpha[rg] = __expf(m_r[rg] - mc);
            m_r[rg] = mc;
            l_r[rg] *= alpha[rg];
        }
#pragma unroll
        for (int dn = 0; dn < 8; dn++)
#pragma unroll
            for (int rg = 0; rg < 4; rg++) accO[dn][rg] *= alpha[rg];
        float ls[4] = {0.f, 0.f, 0.f, 0.f};
#pragma unroll
        for (int n = 0; n < 4; n++) {
#pragma unroll
            for (int rg = 0; rg < 4; rg++) {
                float p = __expf(accS[n][rg] - m_r[rg]);
                ls[rg] += p;
                int pr = lkg * 4 + rg;
                *(unsigned short*)((char*)pt[w] + pr * 128 +
                                   (((n * 16 + lr) * 2) ^ ((pr & 7) << 4))) = f2bf(p);
            }
        }
#pragma unroll
        for (int off = 1; off < 16; off <<= 1)
#pragma unroll
            for (int rg = 0; rg < 4; rg++) ls[rg] += __shfl_xor(ls[rg], off, 64);
#pragma unroll
        for (int rg = 0; rg < 4; rg++) l_r[rg] += ls[rg];
#pragma unroll
        for (int kk2 = 0; kk2 < 2; kk2++) {
            bf16x8 pf = *(const bf16x8*)((const char*)pt[w] + lr * 128 +
                                         (((kk2 * 4 + lkg) ^ (lr & 7)) << 4));
#pragma unroll
            for (int dn = 0; dn < 8; dn++) {
                int r2 = dn * 16 + lr;
                bf16x8 vf = *(const bf16x8*)((const char*)vt + r2 * 128 +
                                             (((kk2 * 4 + lkg) ^ (r2 & 7)) << 4));
                accO[dn] = mfma16(pf, vf, accO[dn]);
            }
        }
    }
#pragma unroll
    for (int dn = 0; dn < 8; dn++) {
#pragma unroll
        for (int rg = 0; rg < 4; rg++) {
            int row = qbk * 64 + w * 16 + lkg * 4 + rg;
            int t = s * LSEQ + row;
            unsigned short* dst = ((t & 1) ? ag : au) + (size_t)(t >> 1) * (NH * HD) +
                                  h * HD + dn * 16 + lr;
            *dst = f2bf(accO[dn][rg] / l_r[rg]);
        }
    }
}

// ---------------- host ----------------
extern "C" void kernel_launch(void* const* d_in, const int* in_sizes, int n_in,
                              void* d_out, int out_size, void* d_ws, size_t ws_size,
                              hipStream_t stream) {
    const float* x    = (const float*)d_in[0];
    const float* cosb = (const float*)d_in[1];
    const float* sinb = (const float*)d_in[2];
    const float* wq   = (const float*)d_in[3];
    const float* bq   = (const float*)d_in[4];
    const float* wk   = (const float*)d_in[5];
    const float* bk   = (const float*)d_in[6];
    const float* wv   = (const float*)d_in[7];
    const float* bv   = (const float*)d_in[8];
    const float* wo   = (const float*)d_in[9];
    const float* wqg  = (const float*)d_in[10];
    const float* bqg  = (const float*)d_in[11];
    const float* wkg  = (const float*)d_in[12];
    const float* bkg  = (const float*)d_in[13];
    const float* wvg  = (const float*)d_in[14];
    const float* bvg  = (const float*)d_in[15];
    const float* wog  = (const float*)d_in[16];
    const float* qn   = (const float*)d_in[17];
    const float* kn   = (const float*)d_in[18];
    const float* qng  = (const float*)d_in[19];
    const float* kng  = (const float*)d_in[20];
    float* out = (float*)d_out;

    char* ws = (char*)d_ws;
    size_t off = 0;
    auto alloc = [&](size_t bytes) -> char* {
        char* p = ws + off;
        off += (bytes + 255) & ~(size_t)255;
        return p;
    };
    const size_t WQ_E = (size_t)3584 * 3584;
    const size_t WK_E = (size_t)512 * 3584;
    unsigned short* wqb  = (unsigned short*)alloc(WQ_E * 2);
    unsigned short* wqgb = (unsigned short*)alloc(WQ_E * 2);
    unsigned short* wob  = (unsigned short*)alloc(WQ_E * 2);
    unsigned short* wogb = (unsigned short*)alloc(WQ_E * 2);
    unsigned short* wkb  = (unsigned short*)alloc(WK_E * 2);
    unsigned short* wkgb = (unsigned short*)alloc(WK_E * 2);
    unsigned short* wvb  = (unsigned short*)alloc(WK_E * 2);
    unsigned short* wvgb = (unsigned short*)alloc(WK_E * 2);
    unsigned short* xu   = (unsigned short*)alloc((size_t)2048 * HID * 2);
    unsigned short* xg   = (unsigned short*)alloc((size_t)2048 * HID * 2);
    float* qf32 = (float*)alloc((size_t)T_TOK * (NH * HD) * 4);
    float* kf32 = (float*)alloc((size_t)T_TOK * (NKV * HD) * 4);
    float* vf32 = (float*)alloc((size_t)T_TOK * (NKV * HD) * 4);
    unsigned short* q_bf = (unsigned short*)alloc((size_t)T_TOK * (NH * HD) * 2);
    unsigned short* k_bf = (unsigned short*)alloc((size_t)T_TOK * (NKV * HD) * 2);
    unsigned short* vTb  = (unsigned short*)alloc((size_t)SEG * NKV * HD * LSEQ * 2);
    unsigned short* au = (unsigned short*)qf32;   // aliases dead qf32
    unsigned short* ag = au + (size_t)2048 * (NH * HD);

    if (ws_size < off) return;

    cvt_x_split<<<T_TOK * (HID / 4) / 256, 256, 0, stream>>>(x, xu, xg);
    cvt_f32_bf16<<<(int)(WQ_E / 4 / 256), 256, 0, stream>>>(wq,  wqb,  (int)(WQ_E / 4));
    cvt_f32_bf16<<<(int)(WQ_E / 4 / 256), 256, 0, stream>>>(wqg, wqgb, (int)(WQ_E / 4));
    cvt_f32_bf16<<<(int)(WQ_E / 4 / 256), 256, 0, stream>>>(wo,  wob,  (int)(WQ_E / 4));
    cvt_f32_bf16<<<(int)(WQ_E / 4 / 256), 256, 0, stream>>>(wog, wogb, (int)(WQ_E / 4));
    cvt_f32_bf16<<<(int)(WK_E / 4 / 256), 256, 0, stream>>>(wk,  wkb,  (int)(WK_E / 4));
    cvt_f32_bf16<<<(int)(WK_E / 4 / 256), 256, 0, stream>>>(wkg, wkgb, (int)(WK_E / 4));
    cvt_f32_bf16<<<(int)(WK_E / 4 / 256), 256, 0, stream>>>(wv,  wvb,  (int)(WK_E / 4));
    cvt_f32_bf16<<<(int)(WK_E / 4 / 256), 256, 0, stream>>>(wvg, wvgb, (int)(WK_E / 4));

    qkv_gemm8<<<dim3(32, 18), 256, 0, stream>>>(xu, xg, wqb, wkb, wvb, wqgb, wkgb, wvgb,
                                                bq, bk, bv, bqg, bkg, bvg, qf32, kf32, vf32);
    normrope2<<<dim3(T_TOK, 8), 256, 0, stream>>>(qf32, kf32, cosb, sinb,
                                                  qn, kn, qng, kng, q_bf, k_bf);
    vtrans<<<dim3(128, 16), 128, 0, stream>>>(vf32, vTb);
    attn_fwd<<<dim3(16, NH, SEG), 256, 0, stream>>>(q_bf, k_bf, vTb, au, ag);
    oproj_gemm8<<<dim3(32, 14), 256, 0, stream>>>(au, ag, wob, wogb, out);
}

// Round 4
// 580.114 us; speedup vs baseline: 1.0091x; 1.0091x over previous
//
#include <hip/hip_runtime.h>
#include <hip/hip_bf16.h>

// Problem constants
#define T_TOK 4096
#define HID   3584
#define NH    28
#define NKV   4
#define HD    128
#define SEG   4
#define LSEQ  1024
#define KDIM  3584   // K of all GEMMs (HID == NH*HD)
#define NT_K  112    // KDIM / 32

typedef __attribute__((ext_vector_type(8))) short bf16x8;
typedef __attribute__((ext_vector_type(4))) float f32x4;

#define GLOAD16(g, l) __builtin_amdgcn_global_load_lds( \
    (const __attribute__((address_space(1))) void*)(g), \
    (__attribute__((address_space(3))) void*)(l), 16, 0, 0)

__device__ __forceinline__ unsigned short f2bf(float f) {
    unsigned u = __float_as_uint(f);
    return (unsigned short)((u + 0x7fffu + ((u >> 16) & 1u)) >> 16);
}

__device__ __forceinline__ f32x4 mfma16(bf16x8 a, bf16x8 b, f32x4 c) {
    return __builtin_amdgcn_mfma_f32_16x16x32_bf16(a, b, c, 0, 0, 0);
}

// ---------------- conversion kernels ----------------

__global__ void cvt_f32_bf16(const float* __restrict__ s, unsigned short* __restrict__ d, int n4) {
    int i = blockIdx.x * 256 + threadIdx.x;
    if (i >= n4) return;
    float4 v = reinterpret_cast<const float4*>(s)[i];
    ushort4 o;
    o.x = f2bf(v.x); o.y = f2bf(v.y); o.z = f2bf(v.z); o.w = f2bf(v.w);
    reinterpret_cast<ushort4*>(d)[i] = o;
}

__global__ void cvt_x_split(const float* __restrict__ x,
                            unsigned short* __restrict__ xu, unsigned short* __restrict__ xg) {
    int i = blockIdx.x * 256 + threadIdx.x;     // over T*HID/4
    int t = i / (HID / 4);
    int c = i - t * (HID / 4);
    float4 v = reinterpret_cast<const float4*>(x)[i];
    ushort4 o;
    o.x = f2bf(v.x); o.y = f2bf(v.y); o.z = f2bf(v.z); o.w = f2bf(v.w);
    unsigned short* dst = ((t & 1) ? xg : xu) + (size_t)(t >> 1) * HID + c * 4;
    *reinterpret_cast<ushort4*>(dst) = o;
}

// ---------------- 128x256 BK=32 ring-3 GEMM core ----------------
// A: 128 rows x KDIM (pre-offset), B: 256 rows x KDIM (weights), C = A @ B^T.
// 256 threads = 4 waves; wave w owns output cols [w*64, w*64+64).
// LDS pair-line layout (replicates R2's measured-zero-conflict geometry):
// 128B lines, line l of a region holds rows {2l, 2l+1} of the K-step (64B each);
// phys 16B-granule p of line l holds logical granule p ^ (l&7), where logical
// granule glog = (row&1)*4 + kchunk. Staged via pre-swizzled global source.
__device__ __forceinline__ void gemm_bm128_core(const unsigned short* __restrict__ Aptr,
                                                const unsigned short* __restrict__ Bptr,
                                                unsigned short* ldsv, f32x4 (&acc)[8][4]) {
    const int tid = threadIdx.x;               // 0..255
    const int lane = tid & 63, w = tid >> 6;
    const int lr = lane & 15, lkg = lane >> 4;
    char* const L = (char*)ldsv;

    // staging: call j covers lines j*32..j*32+31 (rows j*64..j*64+63)
    const int g = (tid & 7) ^ ((tid >> 3) & 7);      // logical granule for this thread
    const int rowbase = 2 * (tid >> 3) + (g >> 2);
    const int koff = (g & 3) * 8;
    size_t src_off[4];
#pragma unroll
    for (int j = 0; j < 4; j++) src_off[j] = (size_t)(j * 64 + rowbase) * KDIM + koff;
    // read: row r, kchunk c -> byte (r>>1)*128 + ((((r&1)<<2)+c) ^ ((r>>1)&7))*16
    const int fcol2 = (lr >> 1) * 128 + (((((lr & 1) << 2) + lkg)) ^ ((lr >> 1) & 7)) * 16;

#pragma unroll
    for (int m = 0; m < 8; m++)
#pragma unroll
        for (int n = 0; n < 4; n++) acc[m][n] = (f32x4){0.f, 0.f, 0.f, 0.f};

#define STG_P1(bufp, k0) do { \
    GLOAD16(Aptr + src_off[0] + (k0), (bufp) + tid * 16); \
    GLOAD16(Aptr + src_off[1] + (k0), (bufp) + 4096 + tid * 16); \
    GLOAD16(Bptr + src_off[0] + (k0), (bufp) + 8192 + tid * 16); } while (0)
#define STG_P2(bufp, k0) do { \
    GLOAD16(Bptr + src_off[1] + (k0), (bufp) + 12288 + tid * 16); \
    GLOAD16(Bptr + src_off[2] + (k0), (bufp) + 16384 + tid * 16); \
    GLOAD16(Bptr + src_off[3] + (k0), (bufp) + 20480 + tid * 16); } while (0)
#define RD_A(bufp, mh) do { _Pragma("unroll") for (int mm = 0; mm < 4; mm++) \
    a[mm] = *(const bf16x8*)((bufp) + ((mh) * 4 + mm) * 1024 + fcol2); } while (0)
#define RD_B(bufp) do { _Pragma("unroll") for (int nn = 0; nn < 4; nn++) \
    b[nn] = *(const bf16x8*)((bufp) + 8192 + w * 4096 + nn * 1024 + fcol2); } while (0)
#define MM(mh) do { _Pragma("unroll") for (int mm = 0; mm < 4; mm++) \
    _Pragma("unroll") for (int nn = 0; nn < 4; nn++) \
        acc[(mh) * 4 + mm][nn] = mfma16(a[mm], b[nn], acc[(mh) * 4 + mm][nn]); } while (0)
#define BAR   asm volatile("s_barrier" ::: "memory")
#define LGKM0 do { asm volatile("s_waitcnt lgkmcnt(0)" ::: "memory"); \
                   __builtin_amdgcn_sched_barrier(0); } while (0)
#define VMC6  asm volatile("s_waitcnt vmcnt(6)" ::: "memory")
#define VMC0  asm volatile("s_waitcnt vmcnt(0)" ::: "memory")
#define PHI   __builtin_amdgcn_s_setprio(1)
#define PLO   __builtin_amdgcn_s_setprio(0)

    char* b0 = L;            // buffer for K-step t
    char* b1 = L + 24576;    // t+1
    char* b2 = L + 49152;    // t+2 (staging target)
    // prologue: stage steps 0 and 1
    STG_P1(b0, 0); STG_P2(b0, 0);
    STG_P1(b1, 32); STG_P2(b1, 32);
    VMC6;   // 12 outstanding -> wait <=6 : buf0's 6 landed
    BAR;

    bf16x8 a[4], b[4];
#pragma unroll 1
    for (int t = 0; t < NT_K; ++t) {
        const int kn = (t + 2) * 32;
        const bool st = (t + 2 < NT_K);
        // P1: read A(m0-3)+B, stage half of step t+2
        RD_A(b0, 0); RD_B(b0);
        if (st) STG_P1(b2, kn);
        BAR; LGKM0; PHI; MM(0); PLO; BAR;
        // P2: read A(m4-7), stage rest of step t+2
        RD_A(b0, 1);
        if (st) STG_P2(b2, kn);
        BAR; LGKM0; PHI; MM(1); PLO;
        if (st) { VMC6; } else { VMC0; }   // drain step t+1's loads (keep t+2's in flight)
        BAR;
        char* tmp = b0; b0 = b1; b1 = b2; b2 = tmp;
    }
    VMC0;

#undef STG_P1
#undef STG_P2
#undef RD_A
#undef RD_B
#undef MM
#undef BAR
#undef LGKM0
#undef VMC6
#undef VMC0
#undef PHI
#undef PLO
}

// ---------------- fused QKV projection ----------------
// flat grid 576 = 32 bm x 18 nb; in-kernel bijective XCD-chunked remap:
// XCD x owns jobs [x*72, (x+1)*72) in n-major order, so each XCD's co-resident
// blocks share ~2 W-panel columns (L2-resident) while A streams via LLC.
__global__ __launch_bounds__(256, 2) void qkv_gemm8(
    const unsigned short* __restrict__ xu, const unsigned short* __restrict__ xg,
    const unsigned short* __restrict__ wq0, const unsigned short* __restrict__ wk0,
    const unsigned short* __restrict__ wv0, const unsigned short* __restrict__ wq1,
    const unsigned short* __restrict__ wk1, const unsigned short* __restrict__ wv1,
    const float* __restrict__ bq0, const float* __restrict__ bk0, const float* __restrict__ bv0,
    const float* __restrict__ bq1, const float* __restrict__ bk1, const float* __restrict__ bv1,
    float* __restrict__ qo, float* __restrict__ ko, float* __restrict__ vo) {
    __shared__ unsigned short lds[36864];   // 72 KiB
    const int bid = blockIdx.x;
    const int job = (bid & 7) * 72 + (bid >> 3);    // 576 = 8 * 72, bijective
    const int bm = job & 31, nb = job >> 5;
    const int par = bm >> 4, mb = bm & 15;
    const unsigned short* A = (par ? xg : xu) + (size_t)mb * 128 * KDIM;
    const unsigned short* W;
    const float* bias;
    float* C;
    int ldc, col0;
    if (nb < 14) {
        W = (par ? wq1 : wq0) + (size_t)nb * 256 * KDIM;
        bias = (par ? bq1 : bq0); C = qo; ldc = NH * HD; col0 = nb * 256;
    } else if (nb < 16) {
        W = (par ? wk1 : wk0) + (size_t)(nb - 14) * 256 * KDIM;
        bias = (par ? bk1 : bk0); C = ko; ldc = NKV * HD; col0 = (nb - 14) * 256;
    } else {
        W = (par ? wv1 : wv0) + (size_t)(nb - 16) * 256 * KDIM;
        bias = (par ? bv1 : bv0); C = vo; ldc = NKV * HD; col0 = (nb - 16) * 256;
    }
    f32x4 acc[8][4];
    gemm_bm128_core(A, W, lds, acc);

    const int lane = threadIdx.x & 63, w = threadIdx.x >> 6;
    const int lr = lane & 15, lkg = lane >> 4;
#pragma unroll
    for (int n = 0; n < 4; n++) {
        int colt = col0 + w * 64 + n * 16 + lr;
        float bb = bias[colt];
#pragma unroll
        for (int m = 0; m < 8; m++) {
#pragma unroll
            for (int rg = 0; rg < 4; rg++) {
                int tr = mb * 128 + m * 16 + lkg * 4 + rg;
                int tok = 2 * tr + par;
                C[(size_t)tok * ldc + colt] = acc[m][n][rg] + bb;
            }
        }
    }
}

// ---------------- output projection ----------------
__global__ __launch_bounds__(256, 2) void oproj_gemm8(
    const unsigned short* __restrict__ au, const unsigned short* __restrict__ ag,
    const unsigned short* __restrict__ wo0, const unsigned short* __restrict__ wo1,
    float* __restrict__ out) {
    __shared__ unsigned short lds[36864];
    const int bid = blockIdx.x;
    const int job = (bid & 7) * 56 + (bid >> 3);    // 448 = 8 * 56, bijective
    const int bm = job & 31, nb = job >> 5;
    const int par = bm >> 4, mb = bm & 15;
    const unsigned short* A = (par ? ag : au) + (size_t)mb * 128 * KDIM;
    const unsigned short* W = (par ? wo1 : wo0) + (size_t)nb * 256 * KDIM;
    f32x4 acc[8][4];
    gemm_bm128_core(A, W, lds, acc);

    const int lane = threadIdx.x & 63, w = threadIdx.x >> 6;
    const int lr = lane & 15, lkg = lane >> 4;
#pragma unroll
    for (int n = 0; n < 4; n++) {
        int col = nb * 256 + w * 64 + n * 16 + lr;
#pragma unroll
        for (int m = 0; m < 8; m++) {
#pragma unroll
            for (int rg = 0; rg < 4; rg++) {
                int tr = mb * 128 + m * 16 + lkg * 4 + rg;
                int tok = 2 * tr + par;
                out[(size_t)tok * HID + col] = acc[m][n][rg];
            }
        }
    }
}

// ---------------- RMSNorm + RoPE (q,k) — 4 waves, no LDS ----------------
__global__ void normrope2(const float* __restrict__ q, const float* __restrict__ k,
                          const float* __restrict__ cosb, const float* __restrict__ sinb,
                          const float* __restrict__ qn, const float* __restrict__ kn,
                          const float* __restrict__ qng, const float* __restrict__ kng,
                          unsigned short* __restrict__ q_bf, unsigned short* __restrict__ k_bf) {
    const int t = blockIdx.x, w = threadIdx.x >> 6, lane = threadIdx.x & 63;
    const int h = blockIdx.y * 4 + w;
    const bool isq = (h < 28);
    const float* src = isq ? q + (size_t)t * (NH * HD) + h * HD
                           : k + (size_t)t * (NKV * HD) + (h - 28) * HD;
    float v0 = src[lane], v1 = src[lane + 64];
    float ss = v0 * v0 + v1 * v1;
#pragma unroll
    for (int off = 32; off >= 1; off >>= 1) ss += __shfl_xor(ss, off, 64);
    float inv = rsqrtf(ss * (1.f / 128.f) + 1e-6f);
    const float* wn = isq ? ((t & 1) ? qng : qn) : ((t & 1) ? kng : kn);
    float n0 = v0 * inv * wn[lane], n1 = v1 * inv * wn[lane + 64];
    float c0 = cosb[(size_t)t * HD + lane], c1 = cosb[(size_t)t * HD + lane + 64];
    float s0 = sinb[(size_t)t * HD + lane], s1 = sinb[(size_t)t * HD + lane + 64];
    float o0 = n0 * c0 - n1 * s0;
    float o1 = n1 * c1 + n0 * s1;
    unsigned short* dst = isq ? q_bf + (size_t)t * (NH * HD) + h * HD
                              : k_bf + (size_t)t * (NKV * HD) + (h - 28) * HD;
    dst[lane] = f2bf(o0);
    dst[lane + 64] = f2bf(o1);
}

// ---------------- V transpose/convert ----------------
__global__ void vtrans(const float* __restrict__ v, unsigned short* __restrict__ vT) {
    const int lb = blockIdx.x, sh = blockIdx.y;
    const int s = sh >> 2, hv = sh & 3, d = threadIdx.x;
    unsigned short tmp[8];
#pragma unroll
    for (int i = 0; i < 8; i++) {
        float val = v[((size_t)(s * LSEQ + lb * 8 + i)) * (NKV * HD) + hv * HD + d];
        tmp[i] = f2bf(val);
    }
    *(bf16x8*)(vT + ((size_t)sh * HD + d) * LSEQ + lb * 8) = *(bf16x8*)tmp;
}

// ---------------- flash attention ----------------
__global__ __launch_bounds__(256, 2) void attn_fwd(
    const unsigned short* __restrict__ q_bf, const unsigned short* __restrict__ k_bf,
    const unsigned short* __restrict__ vT,
    unsigned short* __restrict__ au, unsigned short* __restrict__ ag) {
    __shared__ unsigned short kt[64 * 128];
    __shared__ unsigned short vt[128 * 64];
    __shared__ unsigned short pt[4][16 * 64];

    const int qbk = 15 - blockIdx.x;          // heavy (long-K) blocks dispatch first
    const int h = blockIdx.y, s = blockIdx.z;
    const int hk = h / 7;
    const int tid = threadIdx.x, lane = tid & 63, w = tid >> 6;
    const int lr = lane & 15, lkg = lane >> 4;

    bf16x8 qf[4];
    {
        const unsigned short* qp =
            q_bf + ((size_t)(s * LSEQ + qbk * 64 + w * 16 + lr)) * (NH * HD) + h * HD;
#pragma unroll
        for (int kk = 0; kk < 4; kk++) qf[kk] = *(const bf16x8*)(qp + kk * 32 + lkg * 8);
    }

    float m_r[4] = {-1e30f, -1e30f, -1e30f, -1e30f};
    float l_r[4] = {0.f, 0.f, 0.f, 0.f};
    f32x4 accO[8];
#pragma unroll
    for (int dn = 0; dn < 8; dn++) accO[dn] = (f32x4){0.f, 0.f, 0.f, 0.f};

    const float scale = 0.08838834764831843f;
    const int nkt = qbk + 1;

    for (int ktile = 0; ktile < nkt; ++ktile) {
        __syncthreads();
#pragma unroll
        for (int i = 0; i < 4; i++) {
            int o = i * 4096 + tid * 16;
            {   // K: rows 256B = 16 chunks
                int r = o >> 8;
                int sc = ((o >> 4) & 15) ^ (r & 7);
                GLOAD16(k_bf + ((size_t)(s * LSEQ + ktile * 64 + r)) * (NKV * HD) + hk * HD + sc * 8,
                        (char*)kt + o);
            }
            {   // V^T: rows 128B = 8 chunks
                int r = o >> 7;
                int sc = ((o >> 4) & 7) ^ (r & 7);
                GLOAD16(vT + ((size_t)((s * NKV + hk) * HD + r)) * LSEQ + ktile * 64 + sc * 8,
                        (char*)vt + o);
            }
        }
        __syncthreads();

        f32x4 accS[4];
#pragma unroll
        for (int n = 0; n < 4; n++) accS[n] = (f32x4){0.f, 0.f, 0.f, 0.f};
#pragma unroll
        for (int n = 0; n < 4; n++) {
            int r = n * 16 + lr;
#pragma unroll
            for (int kk = 0; kk < 4; kk++) {
                bf16x8 kf = *(const bf16x8*)((const char*)kt + r * 256 +
                                             (((kk * 4 + lkg) ^ (r & 7)) << 4));
                accS[n] = mfma16(qf[kk], kf, accS[n]);
            }
        }
        float mnew[4] = {-1e30f, -1e30f, -1e30f, -1e30f};
#pragma unroll
        for (int n = 0; n < 4; n++) {
            int col = ktile * 64 + n * 16 + lr;
#pragma unroll
            for (int rg = 0; rg < 4; rg++) {
                int row = qbk * 64 + w * 16 + lkg * 4 + rg;
                float sv = accS[n][rg] * scale;
                sv = (col <= row) ? sv : -1e30f;
                accS[n][rg] = sv;
                mnew[rg] = fmaxf(mnew[rg], sv);
            }
        }
#pragma unroll
        for (int off = 1; off < 16; off <<= 1)
#pragma unroll
            for (int rg = 0; rg < 4; rg++)
                mnew[rg] = fmaxf(mnew[rg], __shfl_xor(mnew[rg], off, 64));
        float alpha[4];
#pragma unroll
        for (int rg = 0; rg < 4; rg++) {
            float mc = fmaxf(m_r[rg], mnew[rg]);
            alpha[rg] = __expf(m_r[rg] - mc);
            m_r[rg] = mc;
            l_r[rg] *= alpha[rg];
        }
#pragma unroll
        for (int dn = 0; dn < 8; dn++)
#pragma unroll
            for (int rg = 0; rg < 4; rg++) accO[dn][rg] *= alpha[rg];
        float ls[4] = {0.f, 0.f, 0.f, 0.f};
#pragma unroll
        for (int n = 0; n < 4; n++) {
#pragma unroll
            for (int rg = 0; rg < 4; rg++) {
                float p = __expf(accS[n][rg] - m_r[rg]);
                ls[rg] += p;
                int pr = lkg * 4 + rg;
                *(unsigned short*)((char*)pt[w] + pr * 128 +
                                   (((n * 16 + lr) * 2) ^ ((pr & 7) << 4))) = f2bf(p);
            }
        }
#pragma unroll
        for (int off = 1; off < 16; off <<= 1)
#pragma unroll
            for (int rg = 0; rg < 4; rg++) ls[rg] += __shfl_xor(ls[rg], off, 64);
#pragma unroll
        for (int rg = 0; rg < 4; rg++) l_r[rg] += ls[rg];
#pragma unroll
        for (int kk2 = 0; kk2 < 2; kk2++) {
            bf16x8 pf = *(const bf16x8*)((const char*)pt[w] + lr * 128 +
                                         (((kk2 * 4 + lkg) ^ (lr & 7)) << 4));
#pragma unroll
            for (int dn = 0; dn < 8; dn++) {
                int r2 = dn * 16 + lr;
                bf16x8 vf = *(const bf16x8*)((const char*)vt + r2 * 128 +
                                             (((kk2 * 4 + lkg) ^ (r2 & 7)) << 4));
                accO[dn] = mfma16(pf, vf, accO[dn]);
            }
        }
    }
#pragma unroll
    for (int dn = 0; dn < 8; dn++) {
#pragma unroll
        for (int rg = 0; rg < 4; rg++) {
            int row = qbk * 64 + w * 16 + lkg * 4 + rg;
            int t = s * LSEQ + row;
            unsigned short* dst = ((t & 1) ? ag : au) + (size_t)(t >> 1) * (NH * HD) +
                                  h * HD + dn * 16 + lr;
            *dst = f2bf(accO[dn][rg] / l_r[rg]);
        }
    }
}

// ---------------- host ----------------
extern "C" void kernel_launch(void* const* d_in, const int* in_sizes, int n_in,
                              void* d_out, int out_size, void* d_ws, size_t ws_size,
                              hipStream_t stream) {
    const float* x    = (const float*)d_in[0];
    const float* cosb = (const float*)d_in[1];
    const float* sinb = (const float*)d_in[2];
    const float* wq   = (const float*)d_in[3];
    const float* bq   = (const float*)d_in[4];
    const float* wk   = (const float*)d_in[5];
    const float* bk   = (const float*)d_in[6];
    const float* wv   = (const float*)d_in[7];
    const float* bv   = (const float*)d_in[8];
    const float* wo   = (const float*)d_in[9];
    const float* wqg  = (const float*)d_in[10];
    const float* bqg  = (const float*)d_in[11];
    const float* wkg  = (const float*)d_in[12];
    const float* bkg  = (const float*)d_in[13];
    const float* wvg  = (const float*)d_in[14];
    const float* bvg  = (const float*)d_in[15];
    const float* wog  = (const float*)d_in[16];
    const float* qn   = (const float*)d_in[17];
    const float* kn   = (const float*)d_in[18];
    const float* qng  = (const float*)d_in[19];
    const float* kng  = (const float*)d_in[20];
    float* out = (float*)d_out;

    char* ws = (char*)d_ws;
    size_t off = 0;
    auto alloc = [&](size_t bytes) -> char* {
        char* p = ws + off;
        off += (bytes + 255) & ~(size_t)255;
        return p;
    };
    const size_t WQ_E = (size_t)3584 * 3584;
    const size_t WK_E = (size_t)512 * 3584;
    unsigned short* wqb  = (unsigned short*)alloc(WQ_E * 2);
    unsigned short* wqgb = (unsigned short*)alloc(WQ_E * 2);
    unsigned short* wob  = (unsigned short*)alloc(WQ_E * 2);
    unsigned short* wogb = (unsigned short*)alloc(WQ_E * 2);
    unsigned short* wkb  = (unsigned short*)alloc(WK_E * 2);
    unsigned short* wkgb = (unsigned short*)alloc(WK_E * 2);
    unsigned short* wvb  = (unsigned short*)alloc(WK_E * 2);
    unsigned short* wvgb = (unsigned short*)alloc(WK_E * 2);
    unsigned short* xu   = (unsigned short*)alloc((size_t)2048 * HID * 2);
    unsigned short* xg   = (unsigned short*)alloc((size_t)2048 * HID * 2);
    float* qf32 = (float*)alloc((size_t)T_TOK * (NH * HD) * 4);
    float* kf32 = (float*)alloc((size_t)T_TOK * (NKV * HD) * 4);
    float* vf32 = (float*)alloc((size_t)T_TOK * (NKV * HD) * 4);
    unsigned short* q_bf = (unsigned short*)alloc((size_t)T_TOK * (NH * HD) * 2);
    unsigned short* k_bf = (unsigned short*)alloc((size_t)T_TOK * (NKV * HD) * 2);
    unsigned short* vTb  = (unsigned short*)alloc((size_t)SEG * NKV * HD * LSEQ * 2);
    unsigned short* au = (unsigned short*)qf32;   // aliases dead qf32
    unsigned short* ag = au + (size_t)2048 * (NH * HD);

    if (ws_size < off) return;

    cvt_x_split<<<T_TOK * (HID / 4) / 256, 256, 0, stream>>>(x, xu, xg);
    cvt_f32_bf16<<<(int)(WQ_E / 4 / 256), 256, 0, stream>>>(wq,  wqb,  (int)(WQ_E / 4));
    cvt_f32_bf16<<<(int)(WQ_E / 4 / 256), 256, 0, stream>>>(wqg, wqgb, (int)(WQ_E / 4));
    cvt_f32_bf16<<<(int)(WQ_E / 4 / 256), 256, 0, stream>>>(wo,  wob,  (int)(WQ_E / 4));
    cvt_f32_bf16<<<(int)(WQ_E / 4 / 256), 256, 0, stream>>>(wog, wogb, (int)(WQ_E / 4));
    cvt_f32_bf16<<<(int)(WK_E / 4 / 256), 256, 0, stream>>>(wk,  wkb,  (int)(WK_E / 4));
    cvt_f32_bf16<<<(int)(WK_E / 4 / 256), 256, 0, stream>>>(wkg, wkgb, (int)(WK_E / 4));
    cvt_f32_bf16<<<(int)(WK_E / 4 / 256), 256, 0, stream>>>(wv,  wvb,  (int)(WK_E / 4));
    cvt_f32_bf16<<<(int)(WK_E / 4 / 256), 256, 0, stream>>>(wvg, wvgb, (int)(WK_E / 4));

    qkv_gemm8<<<dim3(576), 256, 0, stream>>>(xu, xg, wqb, wkb, wvb, wqgb, wkgb, wvgb,
                                             bq, bk, bv, bqg, bkg, bvg, qf32, kf32, vf32);
    normrope2<<<dim3(T_TOK, 8), 256, 0, stream>>>(qf32, kf32, cosb, sinb,
                                                  qn, kn, qng, kng, q_bf, k_bf);
    vtrans<<<dim3(128, 16), 128, 0, stream>>>(vf32, vTb);
    attn_fwd<<<dim3(16, NH, SEG), 256, 0, stream>>>(q_bf, k_bf, vTb, au, ag);
    oproj_gemm8<<<dim3(448), 256, 0, stream>>>(au, ag, wob, wogb, out);
}

// Round 5
// 577.190 us; speedup vs baseline: 1.0142x; 1.0051x over previous
//
#include <hip/hip_runtime.h>
#include <hip/hip_bf16.h>

// Problem constants
#define T_TOK 4096
#define HID   3584
#define NH    28
#define NKV   4
#define HD    128
#define SEG   4
#define LSEQ  1024
#define KDIM  3584   // K of all GEMMs (HID == NH*HD)
#define NT_K  112    // KDIM / 32

typedef __attribute__((ext_vector_type(8))) short bf16x8;
typedef __attribute__((ext_vector_type(4))) float f32x4;

#define GLOAD16(g, l) __builtin_amdgcn_global_load_lds( \
    (const __attribute__((address_space(1))) void*)(g), \
    (__attribute__((address_space(3))) void*)(l), 16, 0, 0)

__device__ __forceinline__ unsigned short f2bf(float f) {
    unsigned u = __float_as_uint(f);
    return (unsigned short)((u + 0x7fffu + ((u >> 16) & 1u)) >> 16);
}

__device__ __forceinline__ f32x4 mfma16(bf16x8 a, bf16x8 b, f32x4 c) {
    return __builtin_amdgcn_mfma_f32_16x16x32_bf16(a, b, c, 0, 0, 0);
}

// ---------------- pack kernels ----------------
// A-pack slot math (inverse of the GEMM's LDS pair-line staging):
// within a 128-row x 32-k step tile (8192 B): row r (0..127), kchunk c (0..3):
// j = r>>6, l = (r&63)>>1, g = (r&1)*4 + c, byte = j*4096 + (l*8 + (g^(l&7)))*16

// x (T,HID) f32 -> packed bf16 A: xp[(par*16+mb)][kstep][8192B]
__global__ void cvt_x_pack(const float* __restrict__ x, unsigned short* __restrict__ xp) {
    const int t = blockIdx.x, c2 = threadIdx.x;   // 448 threads: one 16B chunk each
    const int par = t & 1, tr = t >> 1;
    const int mb = tr >> 7, row = tr & 127;
    const int kstep = c2 >> 2, c = c2 & 3;
    const int j = row >> 6, l = (row & 63) >> 1;
    const int g = (row & 1) * 4 + c;
    const size_t boff = (((size_t)(par * 16 + mb) * 112 + kstep) * 8192) +
                        j * 4096 + (l * 8 + (g ^ (l & 7))) * 16;
    const float* src = x + (size_t)t * HID + c2 * 8;
    unsigned short o[8];
#pragma unroll
    for (int e = 0; e < 8; e++) o[e] = f2bf(src[e]);
    *(bf16x8*)((char*)xp + boff) = *(bf16x8*)o;
}

// attn-out (parity-split bf16 rows [2048][3584]) -> packed A for oproj
__global__ void repack_a(const unsigned short* __restrict__ au, const unsigned short* __restrict__ ag,
                         unsigned short* __restrict__ Ap) {
    const int tr = blockIdx.x, par = blockIdx.y, c2 = threadIdx.x;  // 448 threads
    const int mb = tr >> 7, row = tr & 127;
    const int kstep = c2 >> 2, c = c2 & 3;
    const int j = row >> 6, l = (row & 63) >> 1;
    const int g = (row & 1) * 4 + c;
    const size_t boff = (((size_t)(par * 16 + mb) * 112 + kstep) * 8192) +
                        j * 4096 + (l * 8 + (g ^ (l & 7))) * 16;
    const unsigned short* src = (par ? ag : au) + (size_t)tr * KDIM + c2 * 8;
    *(bf16x8*)((char*)Ap + boff) = *(const bf16x8*)src;
}

// W (ncols x KDIM f32 row-major) -> packed B fragments:
// chunk byte = (((nb*112 + kstep)*4 + w)*4 + nn)*1024 + lane*16
// holds W[nb*256 + w*64 + nn*16 + (lane&15)][kstep*32 + (lane>>4)*8 + 0..7]
// grid (ncols/64, 28 k-tiles of 128), block 256
__global__ void cvt_w_pack(const float* __restrict__ W, unsigned short* __restrict__ Wp) {
    __shared__ float tile[64][132];
    const int cg = blockIdx.x, kt = blockIdx.y, tid = threadIdx.x;
    const int nb = cg >> 2, w = cg & 3;
#pragma unroll
    for (int p = 0; p < 8; p++) {
        int i = tid + 256 * p;
        int row = i >> 5, col = (i & 31) * 4;
        float4 v = *(const float4*)(W + (size_t)(cg * 64 + row) * KDIM + kt * 128 + col);
        tile[row][col] = v.x; tile[row][col + 1] = v.y;
        tile[row][col + 2] = v.z; tile[row][col + 3] = v.w;
    }
    __syncthreads();
#pragma unroll
    for (int p = 0; p < 4; p++) {
        int ch = tid + 256 * p;
        int lane = ch & 63, nn = (ch >> 6) & 3, ks = ch >> 8;
        const float* src = &tile[nn * 16 + (lane & 15)][ks * 32 + (lane >> 4) * 8];
        unsigned short o[8];
#pragma unroll
        for (int e = 0; e < 8; e++) o[e] = f2bf(src[e]);
        size_t boff = ((((size_t)nb * 112 + (kt * 4 + ks)) * 4 + w) * 4 + nn) * 1024 + lane * 16;
        *(bf16x8*)((char*)Wp + boff) = *(bf16x8*)o;
    }
}

// ---------------- 128x256 GEMM core: packed-A LDS ring-3, packed-B direct-to-reg ----------------
// pA: packed A (112 steps x 8192B). pBw: this wave's packed B stream (+t*16384, nn*1024, lane*16).
// 256 threads = 4 waves; wave w owns cols [w*64, w*64+64). One barrier per K-step.
__device__ __forceinline__ void gemm_pack_core(const char* __restrict__ pA,
                                               const char* __restrict__ pBw,
                                               unsigned short* ldsv, f32x4 (&acc)[8][4]) {
    const int tid = threadIdx.x;
    const int lane = tid & 63;
    const int lr = lane & 15, lkg = lane >> 4;
    char* const L = (char*)ldsv;
    // pair-line zero-conflict read offset (R2/R4-verified geometry)
    const int fcol2 = (lr >> 1) * 128 + (((((lr & 1) << 2) + lkg)) ^ ((lr >> 1) & 7)) * 16;

#pragma unroll
    for (int m = 0; m < 8; m++)
#pragma unroll
        for (int n = 0; n < 4; n++) acc[m][n] = (f32x4){0.f, 0.f, 0.f, 0.f};

#define STG(bufp, t) do { \
    GLOAD16(pA + (size_t)(t) * 8192 + tid * 16, (bufp) + tid * 16); \
    GLOAD16(pA + (size_t)(t) * 8192 + 4096 + tid * 16, (bufp) + 4096 + tid * 16); } while (0)
#define LOADB(bb, t) do { _Pragma("unroll") for (int nn = 0; nn < 4; nn++) \
    bb[nn] = *(const bf16x8*)(pBw + (size_t)(t) * 16384 + nn * 1024 + lane * 16); } while (0)
#define RD_A(bufp) do { _Pragma("unroll") for (int mm = 0; mm < 8; mm++) \
    a[mm] = *(const bf16x8*)((bufp) + mm * 1024 + fcol2); } while (0)
#define MMALL(bb) do { _Pragma("unroll") for (int mm = 0; mm < 8; mm++) \
    _Pragma("unroll") for (int nn = 0; nn < 4; nn++) \
        acc[mm][nn] = mfma16(a[mm], bb[nn], acc[mm][nn]); } while (0)
#define BAR   asm volatile("s_barrier" ::: "memory")
#define LGKM0 do { asm volatile("s_waitcnt lgkmcnt(0)" ::: "memory"); \
                   __builtin_amdgcn_sched_barrier(0); } while (0)
#define VMC6  asm volatile("s_waitcnt vmcnt(6)" ::: "memory")
#define VMC4  asm volatile("s_waitcnt vmcnt(4)" ::: "memory")
#define VMC2  asm volatile("s_waitcnt vmcnt(2)" ::: "memory")
#define PHI   __builtin_amdgcn_s_setprio(1)
#define PLO   __builtin_amdgcn_s_setprio(0)

    char* b0 = L;            // A buffer for step t
    char* b1 = L + 8192;     // t+1
    char* b2 = L + 16384;    // t+2 (staging target)
    bf16x8 a[8], bA[4], bB[4];

    // prologue: B(0) to regs; stage A(0), A(1)
    LOADB(bA, 0);
    STG(b0, 0); STG(b1, 1);
    VMC2;   // newer-than-A(0) = STG(1)'s 2 ops
    BAR;

#define STEP(BC, BN, t) do { \
    RD_A(b0); \
    if ((t) + 1 < NT_K) LOADB(BN, (t) + 1); \
    if ((t) + 2 < NT_K) STG(b2, (t) + 2); \
    LGKM0; PHI; MMALL(BC); PLO; \
    if ((t) < NT_K - 2) { VMC6; } else { VMC4; } \
    BAR; \
    char* _tmp = b0; b0 = b1; b1 = b2; b2 = _tmp; } while (0)

#pragma unroll 1
    for (int t2 = 0; t2 < NT_K; t2 += 2) {
        STEP(bA, bB, t2);
        STEP(bB, bA, t2 + 1);
    }

#undef STEP
#undef STG
#undef LOADB
#undef RD_A
#undef MMALL
#undef BAR
#undef LGKM0
#undef VMC6
#undef VMC4
#undef VMC2
#undef PHI
#undef PLO
}

// ---------------- fused QKV projection ----------------
// flat grid 576; XCD n-major remap (8 x 72)
__global__ __launch_bounds__(256, 2) void qkv_gemm8(
    const unsigned short* __restrict__ xp,
    const unsigned short* __restrict__ wqp0, const unsigned short* __restrict__ wkp0,
    const unsigned short* __restrict__ wvp0, const unsigned short* __restrict__ wqp1,
    const unsigned short* __restrict__ wkp1, const unsigned short* __restrict__ wvp1,
    const float* __restrict__ bq0, const float* __restrict__ bk0, const float* __restrict__ bv0,
    const float* __restrict__ bq1, const float* __restrict__ bk1, const float* __restrict__ bv1,
    float* __restrict__ qo, float* __restrict__ ko, float* __restrict__ vo) {
    __shared__ unsigned short lds[12288];   // 24 KiB
    const int bid = blockIdx.x;
    const int job = (bid & 7) * 72 + (bid >> 3);    // 576 = 8 * 72, bijective
    const int bm = job & 31, nb = job >> 5;
    const int par = bm >> 4, mb = bm & 15;
    const int w = threadIdx.x >> 6;
    const char* pA = (const char*)xp + (size_t)(par * 16 + mb) * (112 * 8192);
    const unsigned short* Wsel;
    const float* bias;
    float* C;
    int ldc, col0, nbL;
    if (nb < 14) {
        Wsel = par ? wqp1 : wqp0; nbL = nb;
        bias = (par ? bq1 : bq0); C = qo; ldc = NH * HD; col0 = nb * 256;
    } else if (nb < 16) {
        Wsel = par ? wkp1 : wkp0; nbL = nb - 14;
        bias = (par ? bk1 : bk0); C = ko; ldc = NKV * HD; col0 = (nb - 14) * 256;
    } else {
        Wsel = par ? wvp1 : wvp0; nbL = nb - 16;
        bias = (par ? bv1 : bv0); C = vo; ldc = NKV * HD; col0 = (nb - 16) * 256;
    }
    const char* pBw = (const char*)Wsel + (size_t)nbL * 112 * 16384 + w * 4096;
    f32x4 acc[8][4];
    gemm_pack_core(pA, pBw, lds, acc);

    const int lane = threadIdx.x & 63;
    const int lr = lane & 15, lkg = lane >> 4;
#pragma unroll
    for (int n = 0; n < 4; n++) {
        int colt = col0 + w * 64 + n * 16 + lr;
        float bb = bias[colt];
#pragma unroll
        for (int m = 0; m < 8; m++) {
#pragma unroll
            for (int rg = 0; rg < 4; rg++) {
                int tr = mb * 128 + m * 16 + lkg * 4 + rg;
                int tok = 2 * tr + par;
                C[(size_t)tok * ldc + colt] = acc[m][n][rg] + bb;
            }
        }
    }
}

// ---------------- output projection ----------------
__global__ __launch_bounds__(256, 2) void oproj_gemm8(
    const unsigned short* __restrict__ Ap,
    const unsigned short* __restrict__ wop0, const unsigned short* __restrict__ wop1,
    float* __restrict__ out) {
    __shared__ unsigned short lds[12288];
    const int bid = blockIdx.x;
    const int job = (bid & 7) * 56 + (bid >> 3);    // 448 = 8 * 56, bijective
    const int bm = job & 31, nb = job >> 5;
    const int par = bm >> 4, mb = bm & 15;
    const int w = threadIdx.x >> 6;
    const char* pA = (const char*)Ap + (size_t)(par * 16 + mb) * (112 * 8192);
    const char* pBw = (const char*)(par ? wop1 : wop0) + (size_t)nb * 112 * 16384 + w * 4096;
    f32x4 acc[8][4];
    gemm_pack_core(pA, pBw, lds, acc);

    const int lane = threadIdx.x & 63;
    const int lr = lane & 15, lkg = lane >> 4;
#pragma unroll
    for (int n = 0; n < 4; n++) {
        int col = nb * 256 + w * 64 + n * 16 + lr;
#pragma unroll
        for (int m = 0; m < 8; m++) {
#pragma unroll
            for (int rg = 0; rg < 4; rg++) {
                int tr = mb * 128 + m * 16 + lkg * 4 + rg;
                int tok = 2 * tr + par;
                out[(size_t)tok * HID + col] = acc[m][n][rg];
            }
        }
    }
}

// ---------------- RMSNorm + RoPE (q,k) — 4 waves, no LDS ----------------
__global__ void normrope2(const float* __restrict__ q, const float* __restrict__ k,
                          const float* __restrict__ cosb, const float* __restrict__ sinb,
                          const float* __restrict__ qn, const float* __restrict__ kn,
                          const float* __restrict__ qng, const float* __restrict__ kng,
                          unsigned short* __restrict__ q_bf, unsigned short* __restrict__ k_bf) {
    const int t = blockIdx.x, w = threadIdx.x >> 6, lane = threadIdx.x & 63;
    const int h = blockIdx.y * 4 + w;
    const bool isq = (h < 28);
    const float* src = isq ? q + (size_t)t * (NH * HD) + h * HD
                           : k + (size_t)t * (NKV * HD) + (h - 28) * HD;
    float v0 = src[lane], v1 = src[lane + 64];
    float ss = v0 * v0 + v1 * v1;
#pragma unroll
    for (int off = 32; off >= 1; off >>= 1) ss += __shfl_xor(ss, off, 64);
    float inv = rsqrtf(ss * (1.f / 128.f) + 1e-6f);
    const float* wn = isq ? ((t & 1) ? qng : qn) : ((t & 1) ? kng : kn);
    float n0 = v0 * inv * wn[lane], n1 = v1 * inv * wn[lane + 64];
    float c0 = cosb[(size_t)t * HD + lane], c1 = cosb[(size_t)t * HD + lane + 64];
    float s0 = sinb[(size_t)t * HD + lane], s1 = sinb[(size_t)t * HD + lane + 64];
    float o0 = n0 * c0 - n1 * s0;
    float o1 = n1 * c1 + n0 * s1;
    unsigned short* dst = isq ? q_bf + (size_t)t * (NH * HD) + h * HD
                              : k_bf + (size_t)t * (NKV * HD) + (h - 28) * HD;
    dst[lane] = f2bf(o0);
    dst[lane + 64] = f2bf(o1);
}

// ---------------- V transpose/convert ----------------
__global__ void vtrans(const float* __restrict__ v, unsigned short* __restrict__ vT) {
    const int lb = blockIdx.x, sh = blockIdx.y;
    const int s = sh >> 2, hv = sh & 3, d = threadIdx.x;
    unsigned short tmp[8];
#pragma unroll
    for (int i = 0; i < 8; i++) {
        float val = v[((size_t)(s * LSEQ + lb * 8 + i)) * (NKV * HD) + hv * HD + d];
        tmp[i] = f2bf(val);
    }
    *(bf16x8*)(vT + ((size_t)sh * HD + d) * LSEQ + lb * 8) = *(bf16x8*)tmp;
}

// ---------------- flash attention ----------------
__global__ __launch_bounds__(256, 2) void attn_fwd(
    const unsigned short* __restrict__ q_bf, const unsigned short* __restrict__ k_bf,
    const unsigned short* __restrict__ vT,
    unsigned short* __restrict__ au, unsigned short* __restrict__ ag) {
    __shared__ unsigned short kt[64 * 128];
    __shared__ unsigned short vt[128 * 64];
    __shared__ unsigned short pt[4][16 * 64];

    const int qbk = 15 - blockIdx.x;          // heavy (long-K) blocks dispatch first
    const int h = blockIdx.y, s = blockIdx.z;
    const int hk = h / 7;
    const int tid = threadIdx.x, lane = tid & 63, w = tid >> 6;
    const int lr = lane & 15, lkg = lane >> 4;

    bf16x8 qf[4];
    {
        const unsigned short* qp =
            q_bf + ((size_t)(s * LSEQ + qbk * 64 + w * 16 + lr)) * (NH * HD) + h * HD;
#pragma unroll
        for (int kk = 0; kk < 4; kk++) qf[kk] = *(const bf16x8*)(qp + kk * 32 + lkg * 8);
    }

    float m_r[4] = {-1e30f, -1e30f, -1e30f, -1e30f};
    float l_r[4] = {0.f, 0.f, 0.f, 0.f};
    f32x4 accO[8];
#pragma unroll
    for (int dn = 0; dn < 8; dn++) accO[dn] = (f32x4){0.f, 0.f, 0.f, 0.f};

    const float scale = 0.08838834764831843f;
    const int nkt = qbk + 1;

    for (int ktile = 0; ktile < nkt; ++ktile) {
        __syncthreads();
#pragma unroll
        for (int i = 0; i < 4; i++) {
            int o = i * 4096 + tid * 16;
            {   // K: rows 256B = 16 chunks
                int r = o >> 8;
                int sc = ((o >> 4) & 15) ^ (r & 7);
                GLOAD16(k_bf + ((size_t)(s * LSEQ + ktile * 64 + r)) * (NKV * HD) + hk * HD + sc * 8,
                        (char*)kt + o);
            }
            {   // V^T: rows 128B = 8 chunks
                int r = o >> 7;
                int sc = ((o >> 4) & 7) ^ (r & 7);
                GLOAD16(vT + ((size_t)((s * NKV + hk) * HD + r)) * LSEQ + ktile * 64 + sc * 8,
                        (char*)vt + o);
            }
        }
        __syncthreads();

        f32x4 accS[4];
#pragma unroll
        for (int n = 0; n < 4; n++) accS[n] = (f32x4){0.f, 0.f, 0.f, 0.f};
#pragma unroll
        for (int n = 0; n < 4; n++) {
            int r = n * 16 + lr;
#pragma unroll
            for (int kk = 0; kk < 4; kk++) {
                bf16x8 kf = *(const bf16x8*)((const char*)kt + r * 256 +
                                             (((kk * 4 + lkg) ^ (r & 7)) << 4));
                accS[n] = mfma16(qf[kk], kf, accS[n]);
            }
        }
        float mnew[4] = {-1e30f, -1e30f, -1e30f, -1e30f};
#pragma unroll
        for (int n = 0; n < 4; n++) {
            int col = ktile * 64 + n * 16 + lr;
#pragma unroll
            for (int rg = 0; rg < 4; rg++) {
                int row = qbk * 64 + w * 16 + lkg * 4 + rg;
                float sv = accS[n][rg] * scale;
                sv = (col <= row) ? sv : -1e30f;
                accS[n][rg] = sv;
                mnew[rg] = fmaxf(mnew[rg], sv);
            }
        }
#pragma unroll
        for (int off = 1; off < 16; off <<= 1)
#pragma unroll
            for (int rg = 0; rg < 4; rg++)
                mnew[rg] = fmaxf(mnew[rg], __shfl_xor(mnew[rg], off, 64));
        float alpha[4];
#pragma unroll
        for (int rg = 0; rg < 4; rg++) {
            float mc = fmaxf(m_r[rg], mnew[rg]);
            alpha[rg] = __expf(m_r[rg] - mc);
            m_r[rg] = mc;
            l_r[rg] *= alpha[rg];
        }
#pragma unroll
        for (int dn = 0; dn < 8; dn++)
#pragma unroll
            for (int rg = 0; rg < 4; rg++) accO[dn][rg] *= alpha[rg];
        float ls[4] = {0.f, 0.f, 0.f, 0.f};
#pragma unroll
        for (int n = 0; n < 4; n++) {
#pragma unroll
            for (int rg = 0; rg < 4; rg++) {
                float p = __expf(accS[n][rg] - m_r[rg]);
                ls[rg] += p;
                int pr = lkg * 4 + rg;
                *(unsigned short*)((char*)pt[w] + pr * 128 +
                                   (((n * 16 + lr) * 2) ^ ((pr & 7) << 4))) = f2bf(p);
            }
        }
#pragma unroll
        for (int off = 1; off < 16; off <<= 1)
#pragma unroll
            for (int rg = 0; rg < 4; rg++) ls[rg] += __shfl_xor(ls[rg], off, 64);
#pragma unroll
        for (int rg = 0; rg < 4; rg++) l_r[rg] += ls[rg];
#pragma unroll
        for (int kk2 = 0; kk2 < 2; kk2++) {
            bf16x8 pf = *(const bf16x8*)((const char*)pt[w] + lr * 128 +
                                         (((kk2 * 4 + lkg) ^ (lr & 7)) << 4));
#pragma unroll
            for (int dn = 0; dn < 8; dn++) {
                int r2 = dn * 16 + lr;
                bf16x8 vf = *(const bf16x8*)((const char*)vt + r2 * 128 +
                                             (((kk2 * 4 + lkg) ^ (r2 & 7)) << 4));
                accO[dn] = mfma16(pf, vf, accO[dn]);
            }
        }
    }
#pragma unroll
    for (int dn = 0; dn < 8; dn++) {
#pragma unroll
        for (int rg = 0; rg < 4; rg++) {
            int row = qbk * 64 + w * 16 + lkg * 4 + rg;
            int t = s * LSEQ + row;
            unsigned short* dst = ((t & 1) ? ag : au) + (size_t)(t >> 1) * (NH * HD) +
                                  h * HD + dn * 16 + lr;
            *dst = f2bf(accO[dn][rg] / l_r[rg]);
        }
    }
}

// ---------------- host ----------------
extern "C" void kernel_launch(void* const* d_in, const int* in_sizes, int n_in,
                              void* d_out, int out_size, void* d_ws, size_t ws_size,
                              hipStream_t stream) {
    const float* x    = (const float*)d_in[0];
    const float* cosb = (const float*)d_in[1];
    const float* sinb = (const float*)d_in[2];
    const float* wq   = (const float*)d_in[3];
    const float* bq   = (const float*)d_in[4];
    const float* wk   = (const float*)d_in[5];
    const float* bk   = (const float*)d_in[6];
    const float* wv   = (const float*)d_in[7];
    const float* bv   = (const float*)d_in[8];
    const float* wo   = (const float*)d_in[9];
    const float* wqg  = (const float*)d_in[10];
    const float* bqg  = (const float*)d_in[11];
    const float* wkg  = (const float*)d_in[12];
    const float* bkg  = (const float*)d_in[13];
    const float* wvg  = (const float*)d_in[14];
    const float* bvg  = (const float*)d_in[15];
    const float* wog  = (const float*)d_in[16];
    const float* qn   = (const float*)d_in[17];
    const float* kn   = (const float*)d_in[18];
    const float* qng  = (const float*)d_in[19];
    const float* kng  = (const float*)d_in[20];
    float* out = (float*)d_out;

    char* ws = (char*)d_ws;
    size_t off = 0;
    auto alloc = [&](size_t bytes) -> char* {
        char* p = ws + off;
        off += (bytes + 255) & ~(size_t)255;
        return p;
    };
    const size_t WQ_B = (size_t)3584 * 3584 * 2;   // packed q/o weight bytes
    const size_t WK_B = (size_t)512 * 3584 * 2;    // packed k/v weight bytes
    const size_t AP_B = (size_t)32 * 112 * 8192;   // packed A bytes (28.7 MB)
    unsigned short* wqp0 = (unsigned short*)alloc(WQ_B);
    unsigned short* wqp1 = (unsigned short*)alloc(WQ_B);
    unsigned short* wop0 = (unsigned short*)alloc(WQ_B);
    unsigned short* wop1 = (unsigned short*)alloc(WQ_B);
    unsigned short* wkp0 = (unsigned short*)alloc(WK_B);
    unsigned short* wkp1 = (unsigned short*)alloc(WK_B);
    unsigned short* wvp0 = (unsigned short*)alloc(WK_B);
    unsigned short* wvp1 = (unsigned short*)alloc(WK_B);
    unsigned short* xp   = (unsigned short*)alloc(AP_B);
    float* qf32 = (float*)alloc((size_t)T_TOK * (NH * HD) * 4);
    float* kf32 = (float*)alloc((size_t)T_TOK * (NKV * HD) * 4);
    float* vf32 = (float*)alloc((size_t)T_TOK * (NKV * HD) * 4);
    unsigned short* q_bf = (unsigned short*)alloc((size_t)T_TOK * (NH * HD) * 2);
    unsigned short* k_bf = (unsigned short*)alloc((size_t)T_TOK * (NKV * HD) * 2);
    unsigned short* vTb  = (unsigned short*)alloc((size_t)SEG * NKV * HD * LSEQ * 2);
    unsigned short* au = (unsigned short*)qf32;   // aliases dead qf32 (58.7MB holds 29.4MB)
    unsigned short* ag = au + (size_t)2048 * (NH * HD);
    unsigned short* Apk = xp;                     // aliases xp (dead after qkv_gemm8)

    if (ws_size < off) return;

    cvt_x_pack<<<T_TOK, 448, 0, stream>>>(x, xp);
    cvt_w_pack<<<dim3(56, 28), 256, 0, stream>>>(wq,  wqp0);
    cvt_w_pack<<<dim3(56, 28), 256, 0, stream>>>(wqg, wqp1);
    cvt_w_pack<<<dim3(56, 28), 256, 0, stream>>>(wo,  wop0);
    cvt_w_pack<<<dim3(56, 28), 256, 0, stream>>>(wog, wop1);
    cvt_w_pack<<<dim3(8, 28), 256, 0, stream>>>(wk,  wkp0);
    cvt_w_pack<<<dim3(8, 28), 256, 0, stream>>>(wkg, wkp1);
    cvt_w_pack<<<dim3(8, 28), 256, 0, stream>>>(wv,  wvp0);
    cvt_w_pack<<<dim3(8, 28), 256, 0, stream>>>(wvg, wvp1);

    qkv_gemm8<<<dim3(576), 256, 0, stream>>>(xp, wqp0, wkp0, wvp0, wqp1, wkp1, wvp1,
                                             bq, bk, bv, bqg, bkg, bvg, qf32, kf32, vf32);
    normrope2<<<dim3(T_TOK, 8), 256, 0, stream>>>(qf32, kf32, cosb, sinb,
                                                  qn, kn, qng, kng, q_bf, k_bf);
    vtrans<<<dim3(128, 16), 128, 0, stream>>>(vf32, vTb);
    attn_fwd<<<dim3(16, NH, SEG), 256, 0, stream>>>(q_bf, k_bf, vTb, au, ag);
    repack_a<<<dim3(2048, 2), 448, 0, stream>>>(au, ag, Apk);
    oproj_gemm8<<<dim3(448), 256, 0, stream>>>(Apk, wop0, wop1, out);
}